// Round 12
// baseline (268.380 us; speedup 1.0000x reference)
//
#include <hip/hip_runtime.h>
#include <hip/hip_bf16.h>
#include <math.h>

#define BB 8
#define CC 384
#define HH 14
#define WW 14
#define NHEADS 12
#define RH 7
#define RW 7
#define NN 196
#define SS 49
#define KKK 9
#define SK 58
#define TH 27
#define NTOK 1568

typedef float    f4 __attribute__((ext_vector_type(4)));
typedef _Float16 h8 __attribute__((ext_vector_type(8)));
typedef _Float16 h4 __attribute__((ext_vector_type(4)));

__device__ __forceinline__ float geluf(float x){ return 0.5f*x*(1.0f+erff(x*0.7071067811865475f)); }
__device__ __forceinline__ f4 mfma16h(h8 a, h8 b, f4 c){
  return __builtin_amdgcn_mfma_f32_16x16x32_f16(a, b, c, 0, 0, 0);
}

__constant__ float c_offm[9][2] = {{0,-1},{-1,-1},{-1,0},{-1,1},{0,1},{1,1},{1,0},{1,-1},{0,0}};

// ------------- LDS-tiled transpose B,C,H,W -> B,H,W,C (f32 + fp16) ---------
__global__ void __launch_bounds__(256) k_transpose2(const float* __restrict__ x,
                                                    float* __restrict__ xh, _Float16* __restrict__ xhh){
  __shared__ float tile[48*203];
  int b = blockIdx.x >> 3, c0 = (blockIdx.x & 7)*48;
  int t = threadIdx.x;
  for (int i = t; i < 48*49; i += 256){
    int row = i / 49, seg = i % 49;
    f4 v = *(const f4*)(x + ((size_t)(b*CC + c0 + row))*NN + seg*4);
    #pragma unroll
    for (int j = 0; j < 4; ++j) tile[row*203 + seg*4 + j] = v[j];
  }
  __syncthreads();
  for (int i = t; i < 196*12; i += 256){
    int n = i / 12, seg = i % 12;
    f4 v; h4 vh;
    #pragma unroll
    for (int j = 0; j < 4; ++j){ v[j] = tile[(seg*4 + j)*203 + n]; vh[j] = (_Float16)v[j]; }
    size_t o = ((size_t)(b*NN + n))*CC + c0 + seg*4;
    *(f4*)(xh + o) = v;
    *(h4*)(xhh + o) = vh;
  }
}

// ---------------- staged fp16 hi/lo MFMA GEMM, f32 in/out (R9-proven) -------
template<int EPI>
__global__ void __launch_bounds__(256) k_mmf(const float* __restrict__ A, const float* __restrict__ W,
                                             const float* __restrict__ bias, float* __restrict__ out,
                                             int M, int N){
  __shared__ __align__(16) _Float16 sbuf[10240];
  _Float16* Ah = sbuf; _Float16* Al = sbuf + 2560; _Float16* Bh = sbuf + 5120; _Float16* Bl = sbuf + 7680;
  int t = threadIdx.x;
  int w = t>>6, lane = t&63, col = lane&15, quad = lane>>4;
  int m0 = blockIdx.x*64, n0 = blockIdx.y*64;
  int r = t>>2, cg = t&3;
  int arow = min(m0 + r, M-1);
  int brow = min(n0 + r, N-1);
  f4 acc[4] = {{0,0,0,0},{0,0,0,0},{0,0,0,0},{0,0,0,0}};
  for (int k0 = 0; k0 < 384; k0 += 32){
    f4 a0 = *(const f4*)(A + (size_t)arow*384 + k0 + cg*8);
    f4 a1 = *(const f4*)(A + (size_t)arow*384 + k0 + cg*8 + 4);
    f4 b0 = *(const f4*)(W + (size_t)brow*384 + k0 + cg*8);
    f4 b1 = *(const f4*)(W + (size_t)brow*384 + k0 + cg*8 + 4);
    h8 ah, al, bh, bl;
    #pragma unroll
    for (int j = 0; j < 4; ++j){
      ah[j] = (_Float16)a0[j];   al[j] = (_Float16)(a0[j] - (float)ah[j]);
      ah[4+j] = (_Float16)a1[j]; al[4+j] = (_Float16)(a1[j] - (float)ah[4+j]);
      bh[j] = (_Float16)b0[j];   bl[j] = (_Float16)(b0[j] - (float)bh[j]);
      bh[4+j] = (_Float16)b1[j]; bl[4+j] = (_Float16)(b1[j] - (float)bh[4+j]);
    }
    __syncthreads();
    *(h8*)(Ah + r*40 + cg*8) = ah; *(h8*)(Al + r*40 + cg*8) = al;
    *(h8*)(Bh + r*40 + cg*8) = bh; *(h8*)(Bl + r*40 + cg*8) = bl;
    __syncthreads();
    h8 afh = *(const h8*)(Ah + (w*16+col)*40 + quad*8);
    h8 afl = *(const h8*)(Al + (w*16+col)*40 + quad*8);
    #pragma unroll
    for (int nt = 0; nt < 4; ++nt){
      h8 bfh = *(const h8*)(Bh + (nt*16+col)*40 + quad*8);
      h8 bfl = *(const h8*)(Bl + (nt*16+col)*40 + quad*8);
      acc[nt] = mfma16h(afh, bfh, acc[nt]);
      acc[nt] = mfma16h(afl, bfh, acc[nt]);
      acc[nt] = mfma16h(afh, bfl, acc[nt]);
    }
  }
  if constexpr (EPI == 2){
    float* tile = (float*)sbuf;
    __syncthreads();
    #pragma unroll
    for (int nt = 0; nt < 4; ++nt)
      #pragma unroll
      for (int rr = 0; rr < 4; ++rr)
        tile[(w*16 + quad*4 + rr)*65 + nt*16 + col] = acc[nt][rr];
    __syncthreads();
    for (int i = t; i < 1024; i += 256){
      int o_l = i >> 4, ms = i & 15;
      int m = m0 + ms*4;
      if (m >= M) continue;
      int bb = m / NN, nnn = m % NN;
      int o = n0 + o_l;
      float bo = bias[o];
      f4 v = { tile[(ms*4+0)*65 + o_l] + bo, tile[(ms*4+1)*65 + o_l] + bo,
               tile[(ms*4+2)*65 + o_l] + bo, tile[(ms*4+3)*65 + o_l] + bo };
      *(f4*)(out + ((size_t)bb*384 + o)*NN + nnn) = v;
    }
  } else {
    #pragma unroll
    for (int nt = 0; nt < 4; ++nt){
      #pragma unroll
      for (int rr = 0; rr < 4; ++rr){
        int m = m0 + w*16 + quad*4 + rr;
        int o = n0 + nt*16 + col;
        if (m >= M || o >= N) continue;
        float v = acc[nt][rr] + bias[o];
        if (EPI == 1) v = geluf(v);
        out[(size_t)m*384 + o] = v;
      }
    }
  }
}

// ---------------- depthwise 3x3 s2 conv + LN + GELU (f32) -----------------
__global__ void __launch_bounds__(384) k_dwln(const float* __restrict__ t1,
      const float* __restrict__ Wdw, const float* __restrict__ bdw,
      const float* __restrict__ lng, const float* __restrict__ lnb,
      float* __restrict__ t2){
  int blk = blockIdx.x;
  int ow = blk % RW; int oh = (blk / RW) % RH; int b = blk / (RH*RW);
  int c = threadIdx.x;
  float acc = bdw[c];
  #pragma unroll
  for (int kh = 0; kh < 3; ++kh){
    int ih = oh*2 - 1 + kh;
    if (ih < 0 || ih >= HH) continue;
    #pragma unroll
    for (int kw = 0; kw < 3; ++kw){
      int iw = ow*2 - 1 + kw;
      if (iw < 0 || iw >= WW) continue;
      acc += t1[((b*HH + ih)*WW + iw)*CC + c] * Wdw[c*9 + kh*3 + kw];
    }
  }
  __shared__ float red[6];
  __shared__ float s_mu, s_rv;
  float v = acc;
  #pragma unroll
  for (int o = 32; o > 0; o >>= 1) v += __shfl_down(v, o);
  int wid = c >> 6, lane = c & 63;
  if (lane == 0) red[wid] = v;
  __syncthreads();
  if (c == 0){ float s = 0.f; for (int i = 0; i < 6; ++i) s += red[i]; s_mu = s / CC; }
  __syncthreads();
  float mu = s_mu;
  float d = acc - mu;
  v = d*d;
  #pragma unroll
  for (int o = 32; o > 0; o >>= 1) v += __shfl_down(v, o);
  if (lane == 0) red[wid] = v;
  __syncthreads();
  if (c == 0){ float s = 0.f; for (int i = 0; i < 6; ++i) s += red[i]; s_rv = rsqrtf(s / CC + 1e-5f); }
  __syncthreads();
  float val = d * s_rv * lng[c] + lnb[c];
  t2[blk*CC + c] = geluf(val);
}

// ---------------- merged: offset head GEMM (49 blocks) + qk' GEMM (1800) ----
__global__ void __launch_bounds__(256) k_offqk(const float* __restrict__ t2, const float* __restrict__ Wo2,
                                               float* __restrict__ offp,
                                               const float* __restrict__ qf, const float* __restrict__ Wk,
                                               _Float16* __restrict__ qkh){
  __shared__ __align__(16) _Float16 sbuf[10240];
  _Float16* Ah = sbuf; _Float16* Al = sbuf + 2560; _Float16* Bh = sbuf + 5120; _Float16* Bl = sbuf + 7680;
  int t = threadIdx.x;
  int w = t>>6, lane = t&63, col = lane&15, quad = lane>>4;
  int bid = blockIdx.x;

  if (bid < 49){
    int m0 = (bid/7)*64, n0 = (bid%7)*64;
    int r = t>>2, cg = t&3;
    int arow = min(m0 + r, 391);
    int brow = min(n0 + r, 391);
    f4 acc[4] = {{0,0,0,0},{0,0,0,0},{0,0,0,0},{0,0,0,0}};
    for (int k0 = 0; k0 < 384; k0 += 32){
      f4 a0 = *(const f4*)(t2 + (size_t)arow*384 + k0 + cg*8);
      f4 a1 = *(const f4*)(t2 + (size_t)arow*384 + k0 + cg*8 + 4);
      f4 b0 = *(const f4*)(Wo2 + (size_t)brow*384 + k0 + cg*8);
      f4 b1 = *(const f4*)(Wo2 + (size_t)brow*384 + k0 + cg*8 + 4);
      h8 ah, al, bh, bl;
      #pragma unroll
      for (int j = 0; j < 4; ++j){
        ah[j] = (_Float16)a0[j];   al[j] = (_Float16)(a0[j] - (float)ah[j]);
        ah[4+j] = (_Float16)a1[j]; al[4+j] = (_Float16)(a1[j] - (float)ah[4+j]);
        bh[j] = (_Float16)b0[j];   bl[j] = (_Float16)(b0[j] - (float)bh[j]);
        bh[4+j] = (_Float16)b1[j]; bl[4+j] = (_Float16)(b1[j] - (float)bh[4+j]);
      }
      __syncthreads();
      *(h8*)(Ah + r*40 + cg*8) = ah; *(h8*)(Al + r*40 + cg*8) = al;
      *(h8*)(Bh + r*40 + cg*8) = bh; *(h8*)(Bl + r*40 + cg*8) = bl;
      __syncthreads();
      h8 afh = *(const h8*)(Ah + (w*16+col)*40 + quad*8);
      h8 afl = *(const h8*)(Al + (w*16+col)*40 + quad*8);
      #pragma unroll
      for (int nt = 0; nt < 4; ++nt){
        h8 bfh = *(const h8*)(Bh + (nt*16+col)*40 + quad*8);
        h8 bfl = *(const h8*)(Bl + (nt*16+col)*40 + quad*8);
        acc[nt] = mfma16h(afh, bfh, acc[nt]);
        acc[nt] = mfma16h(afl, bfh, acc[nt]);
        acc[nt] = mfma16h(afh, bfl, acc[nt]);
      }
    }
    #pragma unroll
    for (int nt = 0; nt < 4; ++nt){
      #pragma unroll
      for (int rr = 0; rr < 4; ++rr){
        int row = m0 + w*16 + quad*4 + rr;
        int o = n0 + nt*16 + col;
        if (row < 392 && o < 392){
          int g = o / NN, nn = o % NN;
          int b = row / SS, s = row % SS;
          float rng = (g == 0) ? (1.0f/HH) : (1.0f/WW);
          offp[((b*NN + nn)*SS + s)*2 + g] = tanhf(acc[nt][rr]) * rng * 2.0f;
        }
      }
    }
  } else {
    int idx = bid - 49;
    int m0 = (idx % 25)*64, n0 = ((idx/25) % 6)*64, h = idx/150;
    {
      int r = t>>2, cg = t&3;
      int arow = min(m0 + r, NTOK-1);
      f4 a0 = *(const f4*)(qf + (size_t)arow*384 + h*32 + cg*8);
      f4 a1 = *(const f4*)(qf + (size_t)arow*384 + h*32 + cg*8 + 4);
      h8 ah, al;
      #pragma unroll
      for (int j = 0; j < 4; ++j){
        ah[j] = (_Float16)a0[j];   al[j] = (_Float16)(a0[j] - (float)ah[j]);
        ah[4+j] = (_Float16)a1[j]; al[4+j] = (_Float16)(a1[j] - (float)ah[4+j]);
      }
      *(h8*)(Ah + r*40 + cg*8) = ah; *(h8*)(Al + r*40 + cg*8) = al;
    }
    for (int i = t; i < 2048; i += 256){
      int d = i >> 6, c = i & 63;
      float v = Wk[(size_t)(h*32 + d)*384 + n0 + c];
      _Float16 hi = (_Float16)v;
      Bh[c*40 + d] = hi; Bl[c*40 + d] = (_Float16)(v - (float)hi);
    }
    __syncthreads();
    h8 afh = *(const h8*)(Ah + (w*16+col)*40 + quad*8);
    h8 afl = *(const h8*)(Al + (w*16+col)*40 + quad*8);
    f4 acc[4] = {{0,0,0,0},{0,0,0,0},{0,0,0,0},{0,0,0,0}};
    #pragma unroll
    for (int nt = 0; nt < 4; ++nt){
      h8 bfh = *(const h8*)(Bh + (nt*16+col)*40 + quad*8);
      h8 bfl = *(const h8*)(Bl + (nt*16+col)*40 + quad*8);
      acc[nt] = mfma16h(afh, bfh, acc[nt]);
      acc[nt] = mfma16h(afl, bfh, acc[nt]);
      acc[nt] = mfma16h(afh, bfl, acc[nt]);
    }
    #pragma unroll
    for (int nt = 0; nt < 4; ++nt){
      #pragma unroll
      for (int rr = 0; rr < 4; ++rr){
        int m = m0 + w*16 + quad*4 + rr;
        if (m < NTOK)
          qkh[(size_t)m*4608 + h*384 + n0 + nt*16 + col] = (_Float16)acc[nt][rr];
      }
    }
  }
}

// ---------------- fused per-token attention (G/agg restructure) ------------
// Logits: G[h][i] = qk'_h · xh_i (MFMA vs global xhh), logit = sum_k w_k G[h][i_k]
// Values: agg[h][i] = sum_{s,k:i_k=i} p_s w_k (LDS scatter), fav = agg · xhh (MFMA)
// LDS ~21.5 KB -> 4 blocks/CU.
__global__ void __launch_bounds__(256, 4) k_fused(
    const _Float16* __restrict__ xhh, const float* __restrict__ qf, const float* __restrict__ off,
    const _Float16* __restrict__ qkh,
    const float* __restrict__ bk, const float* __restrict__ Wco, const float* __restrict__ pos,
    _Float16* __restrict__ favh){
  __shared__ float Gagg[12*196];      // G (logit table), later aliased as agg
  __shared__ _Float16 aggh[16*224];   // fav A-operand (heads x positions, padded)
  __shared__ float uni[768];          // qrow[384] -> scoreS[12*64]
  __shared__ float offl[98];
  __shared__ float colb[18];
  __shared__ float qbv[12];
  __shared__ unsigned short stap[232];
  __shared__ float wtap[232];

  float* qrow   = uni;
  float* scoreS = uni;

  int blk = blockIdx.x;
  int n = blk % NN, b = blk / NN;
  int iy = n / WW, ix = n % WW;
  int t = threadIdx.x;
  int w = t>>6, lane = t&63, colh = lane&15, quad = lane>>4;

  // ---- qk prefetch: A-operand of the G-MFMA (12 x h8) ----
  int hclamp = min(colh, 11);
  const _Float16* qbase = qkh + (size_t)blk*4608 + hclamp*384 + quad*8;
  h8 pf[12];
  #pragma unroll
  for (int kt = 0; kt < 12; ++kt) pf[kt] = *(const h8*)(qbase + kt*32);

  // ---- P0: qrow, offl, zero aggh ----
  for (int c = t; c < 384; c += 256) qrow[c] = qf[(size_t)blk*384 + c];
  for (int i = t; i < 98; i += 256) offl[i] = off[(size_t)blk*98 + i];
  for (int i = t; i < 3584; i += 256) aggh[i] = (_Float16)0.f;
  __syncthreads();

  // ---- P1a: colb (co) and qbv[h]=q_h·bk_h ----
  if (t < 144){
    int o = t >> 3, l = t & 7;
    const float* wr = Wco + o*384 + l*48;
    const float* qr = qrow + l*48;
    f4 a4 = {0.f,0.f,0.f,0.f};
    #pragma unroll
    for (int c = 0; c < 48; c += 4) a4 += (*(const f4*)(qr + c)) * (*(const f4*)(wr + c));
    float acc = a4[0]+a4[1]+a4[2]+a4[3];
    acc += __shfl_xor(acc, 1); acc += __shfl_xor(acc, 2); acc += __shfl_xor(acc, 4);
    if (l == 0){
      int g = o & 1;
      float range = (g == 0) ? (1.0f/HH) : (1.0f/WW);
      colb[o] = tanhf(acc) * range;
    }
  }
  if (t >= 160){
    int o = t - 160;
    int h = o >> 3, l = o & 7;
    float acc = 0.f;
    for (int d = l; d < 32; d += 8) acc += qrow[h*32 + d] * bk[h*32 + d];
    acc += __shfl_xor(acc, 1); acc += __shfl_xor(acc, 2); acc += __shfl_xor(acc, 4);
    if (l == 0 && h < 12) qbv[h] = acc;
  }
  __syncthreads();

  const _Float16* xb = xhh + (size_t)b*75264;

  // ---- P2a: taps (t<58) + G MFMA: G[h][i] = qk'_h · xh_i ----
  if (t < SK){
    float cy, cx;
    if (t < SS){
      int sy = t / RW, sx = t % RW;
      cy = offl[t*2+0] + ((2.0f*sy)/13.0f*2.0f - 1.0f);
      cx = offl[t*2+1] + ((2.0f*sx)/13.0f*2.0f - 1.0f);
    } else {
      int kk = t - SS;
      float cyr = fminf(fmaxf((float)iy + c_offm[kk][0], 0.f), (float)HH);
      float cxr = fminf(fmaxf((float)ix + c_offm[kk][1], 0.f), (float)WW);
      cy = colb[kk*2+0] + (cyr/13.0f*2.0f - 1.0f);
      cx = colb[kk*2+1] + (cxr/13.0f*2.0f - 1.0f);
    }
    float py = (cy + 1.0f)*0.5f*13.0f;
    float px = (cx + 1.0f)*0.5f*13.0f;
    float y0 = floorf(py), x0 = floorf(px);
    float wy1 = py - y0, wx1 = px - x0;
    #pragma unroll
    for (int k4 = 0; k4 < 4; ++k4){
      float yf = y0 + (k4 >> 1), xf = x0 + (k4 & 1);
      bool valid = (yf >= 0.f) && (yf <= 13.f) && (xf >= 0.f) && (xf <= 13.f);
      int yi = (int)fminf(fmaxf(yf, 0.f), 13.f);
      int xi = (int)fminf(fmaxf(xf, 0.f), 13.f);
      float wgt = ((k4 >> 1) ? wy1 : (1.f - wy1)) * ((k4 & 1) ? wx1 : (1.f - wx1));
      stap[t*4 + k4] = (unsigned short)(yi*WW + xi);
      wtap[t*4 + k4] = valid ? wgt : 0.f;
    }
  }
  for (int nt = w; nt < 13; nt += 4){
    int i0 = nt*16;
    int icol = min(i0 + colh, 195);
    f4 acc = {0.f,0.f,0.f,0.f};
    #pragma unroll
    for (int kt = 0; kt < 12; ++kt){
      h8 b8 = *(const h8*)(xb + icol*384 + kt*32 + quad*8);
      acc = mfma16h(pf[kt], b8, acc);
    }
    if (i0 + colh < 196){
      #pragma unroll
      for (int r = 0; r < 4; ++r){
        int h = quad*4 + r;
        if (h < 12) Gagg[h*196 + i0 + colh] = acc[r];
      }
    }
  }
  __syncthreads();

  // ---- P2b: logits = bias + qbv + sum_k w_k G[h][i_k] -> scoreS (qrow dead) ----
  for (int i = t; i < SK*NHEADS; i += 256){
    int s = i / NHEADS, h = i - s*NHEADS;
    float ry, rx;
    if (s < SS){
      int sy = s / RW, sx = s % RW;
      ry = (2.0f*sy - iy)/13.0f - offl[s*2+0];
      rx = (2.0f*sx - ix)/13.0f - offl[s*2+1];
    } else {
      int kk = s - SS;
      ry = colb[kk*2+0] - (float)iy;
      rx = colb[kk*2+1] - (float)ix;
    }
    float py = (ry + 1.0f)*0.5f*26.0f;
    float px = (rx + 1.0f)*0.5f*26.0f;
    float y0 = floorf(py), x0 = floorf(px);
    float wy1 = py - y0, wx1 = px - x0;
    float val = qbv[h];
    #pragma unroll
    for (int k4 = 0; k4 < 4; ++k4){
      float yf = y0 + (k4 >> 1), xf = x0 + (k4 & 1);
      if (yf >= 0.f && yf <= 26.f && xf >= 0.f && xf <= 26.f){
        int yi = (int)yf, xi = (int)xf;
        float wgt = ((k4 >> 1) ? wy1 : (1.f - wy1)) * ((k4 & 1) ? wx1 : (1.f - wx1));
        val += pos[(h*TH + yi)*TH + xi] * wgt;
      }
    }
    #pragma unroll
    for (int k4 = 0; k4 < 4; ++k4)
      val += wtap[s*4 + k4] * Gagg[h*196 + stap[s*4 + k4]];
    scoreS[h*64 + s] = val;
  }
  __syncthreads();

  // ---- P3: softmax (waves 0-2) -> probs f32 in scoreS; wave 3 zeros agg ----
  if (t < 192){
    int h = t >> 4, l = t & 15;
    float v[4];
    #pragma unroll
    for (int k = 0; k < 4; ++k){ int s = l + 16*k; v[k] = (s < SK) ? scoreS[h*64 + s] : -1e30f; }
    float mx = fmaxf(fmaxf(v[0], v[1]), fmaxf(v[2], v[3]));
    mx = fmaxf(mx, __shfl_xor(mx, 1)); mx = fmaxf(mx, __shfl_xor(mx, 2));
    mx = fmaxf(mx, __shfl_xor(mx, 4)); mx = fmaxf(mx, __shfl_xor(mx, 8));
    float e[4], sum = 0.f;
    #pragma unroll
    for (int k = 0; k < 4; ++k){ int s = l + 16*k; e[k] = (s < SK) ? expf(v[k] - mx) : 0.f; sum += e[k]; }
    sum += __shfl_xor(sum, 1); sum += __shfl_xor(sum, 2);
    sum += __shfl_xor(sum, 4); sum += __shfl_xor(sum, 8);
    float inv = 1.0f / sum;
    #pragma unroll
    for (int k = 0; k < 4; ++k){
      int s = l + 16*k;
      if (s < SK) scoreS[h*64 + s] = e[k]*inv;
    }
  } else {
    for (int i = t - 192; i < 12*196; i += 64) Gagg[i] = 0.f;   // G dead -> agg
  }
  __syncthreads();

  // ---- P4a: scatter agg[h][i] += p[h][s] * w_k ----
  for (int i = t; i < 232*NHEADS; i += 256){
    int tap = i / NHEADS, h = i - tap*NHEADS;
    int s = tap >> 2;
    float v = scoreS[h*64 + s] * wtap[tap];
    atomicAdd(&Gagg[h*196 + (int)stap[tap]], v);
  }
  __syncthreads();

  // ---- P4b: convert agg f32 -> aggh fp16 [16][224] (pads pre-zeroed) ----
  for (int i = t; i < 12*196; i += 256){
    int m = i / 196, k = i - m*196;
    aggh[m*224 + k] = (_Float16)Gagg[i];
  }
  __syncthreads();

  // ---- P5: fav[h][c] = sum_i agg[h][i] * xh[i][c] (K=224 MFMA, B from global) ----
  for (int nt = w; nt < 24; nt += 4){
    int c = nt*16 + colh;
    f4 acc = {0.f,0.f,0.f,0.f};
    #pragma unroll
    for (int kt = 0; kt < 7; ++kt){
      h8 a8 = *(const h8*)(aggh + colh*224 + kt*32 + quad*8);
      h8 b8;
      #pragma unroll
      for (int j = 0; j < 8; ++j){
        int irow = min(kt*32 + quad*8 + j, 195);
        b8[j] = xb[irow*384 + c];
      }
      acc = mfma16h(a8, b8, acc);
    }
    #pragma unroll
    for (int r = 0; r < 4; ++r){
      int h = quad*4 + r;
      if (h < 12) favh[(size_t)blk*4608 + h*384 + c] = (_Float16)acc[r];
    }
  }
}

// ---------------- per-head Wv MFMA GEMM (no LDS): otok = fav_h·Wv_h + bv ----
__global__ void __launch_bounds__(256) k_wv(const _Float16* __restrict__ favh, const float* __restrict__ Wv,
                                            const float* __restrict__ bv, float* __restrict__ otok){
  int t = threadIdx.x;
  int w = t>>6, lane = t&63, col = lane&15, quad = lane>>4;
  int m0 = blockIdx.x*64; int h = blockIdx.y;
  int arow = min(m0 + w*16 + col, NTOK-1);
  f4 acc[2] = {{0,0,0,0},{0,0,0,0}};
  for (int k0 = 0; k0 < 384; k0 += 32){
    h8 af = *(const h8*)(favh + (size_t)arow*4608 + h*384 + k0 + quad*8);
    #pragma unroll
    for (int nt = 0; nt < 2; ++nt){
      int orow = h*32 + nt*16 + col;
      f4 b0 = *(const f4*)(Wv + (size_t)orow*384 + k0 + quad*8);
      f4 b1 = *(const f4*)(Wv + (size_t)orow*384 + k0 + quad*8 + 4);
      h8 bh, bl;
      #pragma unroll
      for (int j = 0; j < 4; ++j){
        bh[j] = (_Float16)b0[j];   bl[j] = (_Float16)(b0[j] - (float)bh[j]);
        bh[4+j] = (_Float16)b1[j]; bl[4+j] = (_Float16)(b1[j] - (float)bh[4+j]);
      }
      acc[nt] = mfma16h(af, bh, acc[nt]);
      acc[nt] = mfma16h(af, bl, acc[nt]);
    }
  }
  #pragma unroll
  for (int nt = 0; nt < 2; ++nt){
    #pragma unroll
    for (int rr = 0; rr < 4; ++rr){
      int m = m0 + w*16 + quad*4 + rr;
      if (m < NTOK){
        int o = h*32 + nt*16 + col;
        otok[(size_t)m*384 + o] = acc[nt][rr] + bv[o];
      }
    }
  }
}

extern "C" void kernel_launch(void* const* d_in, const int* in_sizes, int n_in,
                              void* d_out, int out_size, void* d_ws, size_t ws_size,
                              hipStream_t stream){
  const float* x    = (const float*)d_in[0];
  const float* Wq   = (const float*)d_in[1];
  const float* bq   = (const float*)d_in[2];
  const float* Wk   = (const float*)d_in[3];
  const float* bk   = (const float*)d_in[4];
  const float* Wv   = (const float*)d_in[5];
  const float* bv   = (const float*)d_in[6];
  const float* Wo1  = (const float*)d_in[7];
  const float* bo1  = (const float*)d_in[8];
  const float* Wdw  = (const float*)d_in[9];
  const float* bdw  = (const float*)d_in[10];
  const float* ln_g = (const float*)d_in[11];
  const float* ln_b = (const float*)d_in[12];
  const float* Wo2  = (const float*)d_in[13];
  const float* Wco  = (const float*)d_in[14];
  const float* pos  = (const float*)d_in[15];
  const float* Wp   = (const float*)d_in[16];
  const float* bp   = (const float*)d_in[17];
  float* out = (float*)d_out;

  float* ws   = (float*)d_ws;
  float* xh   = ws;
  float* qf   = xh   + 602112;
  float* t1   = qf   + 602112;
  float* t2   = t1   + 602112;
  float* offp = t2   + 150528;
  float* otok = offp + 153664;
  _Float16* qkh  = (_Float16*)(otok + 602112);   // 1568*4608 fp16 (~14.45 MB)
  _Float16* favh = qkh;                          // same-token alias (qk prefetched at entry)
  _Float16* xhh  = qkh + 7225344;                // 602112 fp16 (~1.2 MB)

  k_transpose2<<<64, 256, 0, stream>>>(x, xh, xhh);
  k_mmf<0><<<dim3(25,6), 256, 0, stream>>>(xh, Wq,  bq,  qf, NTOK, 384);
  k_mmf<1><<<dim3(25,6), 256, 0, stream>>>(qf, Wo1, bo1, t1, NTOK, 384);
  k_dwln<<<392, 384, 0, stream>>>(t1, Wdw, bdw, ln_g, ln_b, t2);
  k_offqk<<<1849, 256, 0, stream>>>(t2, Wo2, offp, qf, Wk, qkh);
  k_fused<<<1568, 256, 0, stream>>>(xhh, qf, offp, qkh, bk, Wco, pos, favh);
  k_wv<<<dim3(25,12), 256, 0, stream>>>(favh, Wv, bv, otok);
  k_mmf<2><<<dim3(25,6), 256, 0, stream>>>(otok, Wp, bp, out, NTOK, 384);
}

// Round 13
// 228.334 us; speedup vs baseline: 1.1754x; 1.1754x over previous
//
#include <hip/hip_runtime.h>
#include <hip/hip_bf16.h>
#include <math.h>

#define BB 8
#define CC 384
#define HH 14
#define WW 14
#define NHEADS 12
#define RH 7
#define RW 7
#define NN 196
#define SS 49
#define KKK 9
#define SK 58
#define TH 27
#define NTOK 1568

typedef float    f4 __attribute__((ext_vector_type(4)));
typedef _Float16 h8 __attribute__((ext_vector_type(8)));
typedef _Float16 h4 __attribute__((ext_vector_type(4)));

__device__ __forceinline__ float geluf(float x){ return 0.5f*x*(1.0f+erff(x*0.7071067811865475f)); }
__device__ __forceinline__ f4 mfma16h(h8 a, h8 b, f4 c){
  return __builtin_amdgcn_mfma_f32_16x16x32_f16(a, b, c, 0, 0, 0);
}

__constant__ float c_offm[9][2] = {{0,-1},{-1,-1},{-1,0},{-1,1},{0,1},{1,1},{1,0},{1,-1},{0,0}};

// ------------- LDS-tiled transpose B,C,H,W -> B,H,W,C (f32 + fp16) ---------
__global__ void __launch_bounds__(256) k_transpose2(const float* __restrict__ x,
                                                    float* __restrict__ xh, _Float16* __restrict__ xhh){
  __shared__ float tile[48*203];
  int b = blockIdx.x >> 3, c0 = (blockIdx.x & 7)*48;
  int t = threadIdx.x;
  for (int i = t; i < 48*49; i += 256){
    int row = i / 49, seg = i % 49;
    f4 v = *(const f4*)(x + ((size_t)(b*CC + c0 + row))*NN + seg*4);
    #pragma unroll
    for (int j = 0; j < 4; ++j) tile[row*203 + seg*4 + j] = v[j];
  }
  __syncthreads();
  for (int i = t; i < 196*12; i += 256){
    int n = i / 12, seg = i % 12;
    f4 v; h4 vh;
    #pragma unroll
    for (int j = 0; j < 4; ++j){ v[j] = tile[(seg*4 + j)*203 + n]; vh[j] = (_Float16)v[j]; }
    size_t o = ((size_t)(b*NN + n))*CC + c0 + seg*4;
    *(f4*)(xh + o) = v;
    *(h4*)(xhh + o) = vh;
  }
}

// -------- staged fp16 hi/lo MFMA GEMM, f32 in; EPI: 0 plain, 1 gelu,
//          2 transpose-scatter f32, 3 fp16 out no bias --------
template<int EPI>
__global__ void __launch_bounds__(256) k_mmf(const float* __restrict__ A, const float* __restrict__ W,
                                             const float* __restrict__ bias, float* __restrict__ out,
                                             _Float16* __restrict__ out16, int M, int N){
  __shared__ __align__(16) _Float16 sbuf[10240];
  _Float16* Ah = sbuf; _Float16* Al = sbuf + 2560; _Float16* Bh = sbuf + 5120; _Float16* Bl = sbuf + 7680;
  int t = threadIdx.x;
  int w = t>>6, lane = t&63, col = lane&15, quad = lane>>4;
  int m0 = blockIdx.x*64, n0 = blockIdx.y*64;
  int r = t>>2, cg = t&3;
  int arow = min(m0 + r, M-1);
  int brow = min(n0 + r, N-1);
  f4 acc[4] = {{0,0,0,0},{0,0,0,0},{0,0,0,0},{0,0,0,0}};
  for (int k0 = 0; k0 < 384; k0 += 32){
    f4 a0 = *(const f4*)(A + (size_t)arow*384 + k0 + cg*8);
    f4 a1 = *(const f4*)(A + (size_t)arow*384 + k0 + cg*8 + 4);
    f4 b0 = *(const f4*)(W + (size_t)brow*384 + k0 + cg*8);
    f4 b1 = *(const f4*)(W + (size_t)brow*384 + k0 + cg*8 + 4);
    h8 ah, al, bh, bl;
    #pragma unroll
    for (int j = 0; j < 4; ++j){
      ah[j] = (_Float16)a0[j];   al[j] = (_Float16)(a0[j] - (float)ah[j]);
      ah[4+j] = (_Float16)a1[j]; al[4+j] = (_Float16)(a1[j] - (float)ah[4+j]);
      bh[j] = (_Float16)b0[j];   bl[j] = (_Float16)(b0[j] - (float)bh[j]);
      bh[4+j] = (_Float16)b1[j]; bl[4+j] = (_Float16)(b1[j] - (float)bh[4+j]);
    }
    __syncthreads();
    *(h8*)(Ah + r*40 + cg*8) = ah; *(h8*)(Al + r*40 + cg*8) = al;
    *(h8*)(Bh + r*40 + cg*8) = bh; *(h8*)(Bl + r*40 + cg*8) = bl;
    __syncthreads();
    h8 afh = *(const h8*)(Ah + (w*16+col)*40 + quad*8);
    h8 afl = *(const h8*)(Al + (w*16+col)*40 + quad*8);
    #pragma unroll
    for (int nt = 0; nt < 4; ++nt){
      h8 bfh = *(const h8*)(Bh + (nt*16+col)*40 + quad*8);
      h8 bfl = *(const h8*)(Bl + (nt*16+col)*40 + quad*8);
      acc[nt] = mfma16h(afh, bfh, acc[nt]);
      acc[nt] = mfma16h(afl, bfh, acc[nt]);
      acc[nt] = mfma16h(afh, bfl, acc[nt]);
    }
  }
  if constexpr (EPI == 2){
    float* tile = (float*)sbuf;
    __syncthreads();
    #pragma unroll
    for (int nt = 0; nt < 4; ++nt)
      #pragma unroll
      for (int rr = 0; rr < 4; ++rr)
        tile[(w*16 + quad*4 + rr)*65 + nt*16 + col] = acc[nt][rr];
    __syncthreads();
    for (int i = t; i < 1024; i += 256){
      int o_l = i >> 4, ms = i & 15;
      int m = m0 + ms*4;
      if (m >= M) continue;
      int bb = m / NN, nnn = m % NN;
      int o = n0 + o_l;
      float bo = bias[o];
      f4 v = { tile[(ms*4+0)*65 + o_l] + bo, tile[(ms*4+1)*65 + o_l] + bo,
               tile[(ms*4+2)*65 + o_l] + bo, tile[(ms*4+3)*65 + o_l] + bo };
      *(f4*)(out + ((size_t)bb*384 + o)*NN + nnn) = v;
    }
  } else {
    #pragma unroll
    for (int nt = 0; nt < 4; ++nt){
      #pragma unroll
      for (int rr = 0; rr < 4; ++rr){
        int m = m0 + w*16 + quad*4 + rr;
        int o = n0 + nt*16 + col;
        if (m >= M || o >= N) continue;
        if constexpr (EPI == 3){
          out16[(size_t)m*384 + o] = (_Float16)acc[nt][rr];
        } else {
          float v = acc[nt][rr] + bias[o];
          if (EPI == 1) v = geluf(v);
          out[(size_t)m*384 + o] = v;
        }
      }
    }
  }
}

// ---------------- depthwise 3x3 s2 conv + LN + GELU (f32) -----------------
__global__ void __launch_bounds__(384) k_dwln(const float* __restrict__ t1,
      const float* __restrict__ Wdw, const float* __restrict__ bdw,
      const float* __restrict__ lng, const float* __restrict__ lnb,
      float* __restrict__ t2){
  int blk = blockIdx.x;
  int ow = blk % RW; int oh = (blk / RW) % RH; int b = blk / (RH*RW);
  int c = threadIdx.x;
  float acc = bdw[c];
  #pragma unroll
  for (int kh = 0; kh < 3; ++kh){
    int ih = oh*2 - 1 + kh;
    if (ih < 0 || ih >= HH) continue;
    #pragma unroll
    for (int kw = 0; kw < 3; ++kw){
      int iw = ow*2 - 1 + kw;
      if (iw < 0 || iw >= WW) continue;
      acc += t1[((b*HH + ih)*WW + iw)*CC + c] * Wdw[c*9 + kh*3 + kw];
    }
  }
  __shared__ float red[6];
  __shared__ float s_mu, s_rv;
  float v = acc;
  #pragma unroll
  for (int o = 32; o > 0; o >>= 1) v += __shfl_down(v, o);
  int wid = c >> 6, lane = c & 63;
  if (lane == 0) red[wid] = v;
  __syncthreads();
  if (c == 0){ float s = 0.f; for (int i = 0; i < 6; ++i) s += red[i]; s_mu = s / CC; }
  __syncthreads();
  float mu = s_mu;
  float d = acc - mu;
  v = d*d;
  #pragma unroll
  for (int o = 32; o > 0; o >>= 1) v += __shfl_down(v, o);
  if (lane == 0) red[wid] = v;
  __syncthreads();
  if (c == 0){ float s = 0.f; for (int i = 0; i < 6; ++i) s += red[i]; s_rv = rsqrtf(s / CC + 1e-5f); }
  __syncthreads();
  float val = d * s_rv * lng[c] + lnb[c];
  t2[blk*CC + c] = geluf(val);
}

// ------- merged: offset head GEMM (49 blocks) + VprojT GEMM (192 blocks) ----
// VprojT[b][o][i] = sum_c Wv[o][c]*xhh_b[i][c]; i padded to 224 (zeros for i>=196)
__global__ void __launch_bounds__(256) k_misc(const float* __restrict__ t2, const float* __restrict__ Wo2,
                                              float* __restrict__ offp,
                                              const _Float16* __restrict__ xhh, const float* __restrict__ Wv,
                                              _Float16* __restrict__ VprojT){
  __shared__ __align__(16) _Float16 sbuf[10240];
  _Float16* Ah = sbuf; _Float16* Al = sbuf + 2560; _Float16* Bh = sbuf + 5120; _Float16* Bl = sbuf + 7680;
  int t = threadIdx.x;
  int w = t>>6, lane = t&63, col = lane&15, quad = lane>>4;
  int bid = blockIdx.x;

  if (bid < 49){
    int m0 = (bid/7)*64, n0 = (bid%7)*64;
    int r = t>>2, cg = t&3;
    int arow = min(m0 + r, 391);
    int brow = min(n0 + r, 391);
    f4 acc[4] = {{0,0,0,0},{0,0,0,0},{0,0,0,0},{0,0,0,0}};
    for (int k0 = 0; k0 < 384; k0 += 32){
      f4 a0 = *(const f4*)(t2 + (size_t)arow*384 + k0 + cg*8);
      f4 a1 = *(const f4*)(t2 + (size_t)arow*384 + k0 + cg*8 + 4);
      f4 b0 = *(const f4*)(Wo2 + (size_t)brow*384 + k0 + cg*8);
      f4 b1 = *(const f4*)(Wo2 + (size_t)brow*384 + k0 + cg*8 + 4);
      h8 ah, al, bh, bl;
      #pragma unroll
      for (int j = 0; j < 4; ++j){
        ah[j] = (_Float16)a0[j];   al[j] = (_Float16)(a0[j] - (float)ah[j]);
        ah[4+j] = (_Float16)a1[j]; al[4+j] = (_Float16)(a1[j] - (float)ah[4+j]);
        bh[j] = (_Float16)b0[j];   bl[j] = (_Float16)(b0[j] - (float)bh[j]);
        bh[4+j] = (_Float16)b1[j]; bl[4+j] = (_Float16)(b1[j] - (float)bh[4+j]);
      }
      __syncthreads();
      *(h8*)(Ah + r*40 + cg*8) = ah; *(h8*)(Al + r*40 + cg*8) = al;
      *(h8*)(Bh + r*40 + cg*8) = bh; *(h8*)(Bl + r*40 + cg*8) = bl;
      __syncthreads();
      h8 afh = *(const h8*)(Ah + (w*16+col)*40 + quad*8);
      h8 afl = *(const h8*)(Al + (w*16+col)*40 + quad*8);
      #pragma unroll
      for (int nt = 0; nt < 4; ++nt){
        h8 bfh = *(const h8*)(Bh + (nt*16+col)*40 + quad*8);
        h8 bfl = *(const h8*)(Bl + (nt*16+col)*40 + quad*8);
        acc[nt] = mfma16h(afh, bfh, acc[nt]);
        acc[nt] = mfma16h(afl, bfh, acc[nt]);
        acc[nt] = mfma16h(afh, bfl, acc[nt]);
      }
    }
    #pragma unroll
    for (int nt = 0; nt < 4; ++nt){
      #pragma unroll
      for (int rr = 0; rr < 4; ++rr){
        int row = m0 + w*16 + quad*4 + rr;
        int o = n0 + nt*16 + col;
        if (row < 392 && o < 392){
          int g = o / NN, nn = o % NN;
          int b = row / SS, s = row % SS;
          float rng = (g == 0) ? (1.0f/HH) : (1.0f/WW);
          offp[((b*NN + nn)*SS + s)*2 + g] = tanhf(acc[nt][rr]) * rng * 2.0f;
        }
      }
    }
  } else {
    // VprojT: direct-fragment GEMM, M=o(384), N=i(224 padded), K=c(384)
    int idx = bid - 49;
    int mo = idx % 6;
    int ny = (idx / 6) % 4;
    int b  = idx / 24;
    int m0 = mo*64, n0 = ny*64;
    int orow = m0 + w*16 + col;                 // A row (lane col)
    const float* wvr = Wv + (size_t)orow*384;
    f4 acc[4] = {{0,0,0,0},{0,0,0,0},{0,0,0,0},{0,0,0,0}};
    for (int kt = 0; kt < 12; ++kt){
      f4 a0 = *(const f4*)(wvr + kt*32 + quad*8);
      f4 a1 = *(const f4*)(wvr + kt*32 + quad*8 + 4);
      h8 ah, al;
      #pragma unroll
      for (int j = 0; j < 4; ++j){
        ah[j] = (_Float16)a0[j];   al[j] = (_Float16)(a0[j] - (float)ah[j]);
        ah[4+j] = (_Float16)a1[j]; al[4+j] = (_Float16)(a1[j] - (float)ah[4+j]);
      }
      #pragma unroll
      for (int nt = 0; nt < 4; ++nt){
        int i = min(n0 + nt*16 + col, 195);
        h8 b8 = *(const h8*)(xhh + ((size_t)(b*196 + i))*384 + kt*32 + quad*8);
        acc[nt] = mfma16h(ah, b8, acc[nt]);
        acc[nt] = mfma16h(al, b8, acc[nt]);
      }
    }
    #pragma unroll
    for (int nt = 0; nt < 4; ++nt){
      #pragma unroll
      for (int rr = 0; rr < 4; ++rr){
        int o = m0 + w*16 + quad*4 + rr;
        int i = n0 + nt*16 + col;
        if (i < 224)
          VprojT[((size_t)(b*384 + o))*224 + i] = (i < 196) ? (_Float16)acc[nt][rr] : (_Float16)0.f;
      }
    }
  }
}

// -------- G-GEMM: G[tok][h*196+i] = q[tok]_h · K2[b,i]_h  (per (b,h)) -------
__global__ void __launch_bounds__(256) k_qkt(const float* __restrict__ qf, const _Float16* __restrict__ K2h,
                                             _Float16* __restrict__ G16){
  int t = threadIdx.x;
  int w = t>>6, lane = t&63, col = lane&15, quad = lane>>4;
  int m0 = blockIdx.x*64;
  int bh = blockIdx.y; int b = bh / 12, h = bh - b*12;
  // A fragment: q (f32 -> fp16), lane m=col, k=quad*8+j over head dims (K=32)
  const float* qr = qf + ((size_t)(b*196 + min(m0 + w*16 + col, 195)))*384 + h*32;
  f4 q0 = *(const f4*)(qr + quad*8);
  f4 q1 = *(const f4*)(qr + quad*8 + 4);
  h8 a8;
  #pragma unroll
  for (int j = 0; j < 4; ++j){ a8[j] = (_Float16)q0[j]; a8[4+j] = (_Float16)q1[j]; }
  f4 acc[13];
  #pragma unroll
  for (int nt = 0; nt < 13; ++nt){
    int i = min(nt*16 + col, 195);
    h8 b8 = *(const h8*)(K2h + ((size_t)(b*196 + i))*384 + h*32 + quad*8);
    f4 z = {0.f,0.f,0.f,0.f};
    acc[nt] = mfma16h(a8, b8, z);
  }
  #pragma unroll
  for (int nt = 0; nt < 13; ++nt){
    #pragma unroll
    for (int r = 0; r < 4; ++r){
      int m = m0 + w*16 + quad*4 + r;
      int i = nt*16 + col;
      if (m < 196 && i < 196)
        G16[((size_t)(b*196 + m))*2352 + h*196 + i] = (_Float16)acc[nt][r];
    }
  }
}

// ---------------- fused per-token: taps + softmax + agg scatter (no MFMA) ---
__global__ void __launch_bounds__(256, 6) k_fused(
    const float* __restrict__ qf, const float* __restrict__ off,
    const _Float16* __restrict__ G16,
    const float* __restrict__ bk, const float* __restrict__ Wco, const float* __restrict__ pos,
    _Float16* __restrict__ agg16){
  __shared__ _Float16 Gs[2352];
  __shared__ float agg[2688];          // [h*224+i] f32; front 384 aliases qrow
  __shared__ float scoreS[696];        // [h*58+s]
  __shared__ float offl[98];
  __shared__ float colb[18];
  __shared__ float qbv[12];
  __shared__ unsigned short stap[232];
  __shared__ float wtap[232];
  float* qrow = agg;

  int blk = blockIdx.x;
  int n = blk % NN, b = blk / NN;
  int iy = n / WW, ix = n % WW;
  int t = threadIdx.x;

  // ---- P0 ----
  {
    const _Float16* gr = G16 + (size_t)blk*2352;
    for (int i = t; i < 2352; i += 256) Gs[i] = gr[i];
  }
  for (int c = t; c < 384; c += 256) qrow[c] = qf[(size_t)blk*384 + c];
  for (int i = t; i < 98; i += 256) offl[i] = off[(size_t)blk*98 + i];
  __syncthreads();

  // ---- P1a: colb (co) and qbv[h] = q_h·bk_h ----
  if (t < 144){
    int o = t >> 3, l = t & 7;
    const float* wr = Wco + o*384 + l*48;
    const float* qr = qrow + l*48;
    f4 a4 = {0.f,0.f,0.f,0.f};
    #pragma unroll
    for (int c = 0; c < 48; c += 4) a4 += (*(const f4*)(qr + c)) * (*(const f4*)(wr + c));
    float acc = a4[0]+a4[1]+a4[2]+a4[3];
    acc += __shfl_xor(acc, 1); acc += __shfl_xor(acc, 2); acc += __shfl_xor(acc, 4);
    if (l == 0){
      int g = o & 1;
      float range = (g == 0) ? (1.0f/HH) : (1.0f/WW);
      colb[o] = tanhf(acc) * range;
    }
  }
  if (t >= 160){
    int o = t - 160;
    int h = o >> 3, l = o & 7;
    float acc = 0.f;
    for (int d = l; d < 32; d += 8) acc += qrow[h*32 + d] * bk[h*32 + d];
    acc += __shfl_xor(acc, 1); acc += __shfl_xor(acc, 2); acc += __shfl_xor(acc, 4);
    if (l == 0 && h < 12) qbv[h] = acc;
  }
  __syncthreads();

  // ---- P1b: taps (t<58) + zero agg (qrow dead) ----
  if (t < SK){
    float cy, cx;
    if (t < SS){
      int sy = t / RW, sx = t % RW;
      cy = offl[t*2+0] + ((2.0f*sy)/13.0f*2.0f - 1.0f);
      cx = offl[t*2+1] + ((2.0f*sx)/13.0f*2.0f - 1.0f);
    } else {
      int kk = t - SS;
      float cyr = fminf(fmaxf((float)iy + c_offm[kk][0], 0.f), (float)HH);
      float cxr = fminf(fmaxf((float)ix + c_offm[kk][1], 0.f), (float)WW);
      cy = colb[kk*2+0] + (cyr/13.0f*2.0f - 1.0f);
      cx = colb[kk*2+1] + (cxr/13.0f*2.0f - 1.0f);
    }
    float py = (cy + 1.0f)*0.5f*13.0f;
    float px = (cx + 1.0f)*0.5f*13.0f;
    float y0 = floorf(py), x0 = floorf(px);
    float wy1 = py - y0, wx1 = px - x0;
    #pragma unroll
    for (int k4 = 0; k4 < 4; ++k4){
      float yf = y0 + (k4 >> 1), xf = x0 + (k4 & 1);
      bool valid = (yf >= 0.f) && (yf <= 13.f) && (xf >= 0.f) && (xf <= 13.f);
      int yi = (int)fminf(fmaxf(yf, 0.f), 13.f);
      int xi = (int)fminf(fmaxf(xf, 0.f), 13.f);
      float wgt = ((k4 >> 1) ? wy1 : (1.f - wy1)) * ((k4 & 1) ? wx1 : (1.f - wx1));
      stap[t*4 + k4] = (unsigned short)(yi*WW + xi);
      wtap[t*4 + k4] = valid ? wgt : 0.f;
    }
  }
  __syncthreads();   // taps + colb ready; now zero agg (all threads)
  for (int i = t; i < 2688; i += 256) agg[i] = 0.f;

  // ---- P2: logits = qbv + relpos-bias + sum_k w_k * Gs[h][i_k] ----
  for (int i = t; i < SK*NHEADS; i += 256){
    int s = i / NHEADS, h = i - s*NHEADS;
    float ry, rx;
    if (s < SS){
      int sy = s / RW, sx = s % RW;
      ry = (2.0f*sy - iy)/13.0f - offl[s*2+0];
      rx = (2.0f*sx - ix)/13.0f - offl[s*2+1];
    } else {
      int kk = s - SS;
      ry = colb[kk*2+0] - (float)iy;
      rx = colb[kk*2+1] - (float)ix;
    }
    float py = (ry + 1.0f)*0.5f*26.0f;
    float px = (rx + 1.0f)*0.5f*26.0f;
    float y0 = floorf(py), x0 = floorf(px);
    float wy1 = py - y0, wx1 = px - x0;
    float val = qbv[h];
    #pragma unroll
    for (int k4 = 0; k4 < 4; ++k4){
      float yf = y0 + (k4 >> 1), xf = x0 + (k4 & 1);
      if (yf >= 0.f && yf <= 26.f && xf >= 0.f && xf <= 26.f){
        int yi = (int)yf, xi = (int)xf;
        float wgt = ((k4 >> 1) ? wy1 : (1.f - wy1)) * ((k4 & 1) ? wx1 : (1.f - wx1));
        val += pos[(h*TH + yi)*TH + xi] * wgt;
      }
    }
    #pragma unroll
    for (int k4 = 0; k4 < 4; ++k4)
      val += wtap[s*4 + k4] * (float)Gs[h*196 + stap[s*4 + k4]];
    scoreS[h*58 + s] = val;
  }
  __syncthreads();

  // ---- P3: softmax per head (192 threads) -> probs back into scoreS ----
  if (t < 192){
    int h = t >> 4, l = t & 15;
    float v[4];
    #pragma unroll
    for (int k = 0; k < 4; ++k){ int s = l + 16*k; v[k] = (s < SK) ? scoreS[h*58 + s] : -1e30f; }
    float mx = fmaxf(fmaxf(v[0], v[1]), fmaxf(v[2], v[3]));
    mx = fmaxf(mx, __shfl_xor(mx, 1)); mx = fmaxf(mx, __shfl_xor(mx, 2));
    mx = fmaxf(mx, __shfl_xor(mx, 4)); mx = fmaxf(mx, __shfl_xor(mx, 8));
    float e[4], sum = 0.f;
    #pragma unroll
    for (int k = 0; k < 4; ++k){ int s = l + 16*k; e[k] = (s < SK) ? expf(v[k] - mx) : 0.f; sum += e[k]; }
    sum += __shfl_xor(sum, 1); sum += __shfl_xor(sum, 2);
    sum += __shfl_xor(sum, 4); sum += __shfl_xor(sum, 8);
    float inv = 1.0f / sum;
    #pragma unroll
    for (int k = 0; k < 4; ++k){
      int s = l + 16*k;
      if (s < SK) scoreS[h*58 + s] = e[k]*inv;
    }
  }
  __syncthreads();

  // ---- P4: scatter agg[h][i] += p[h][s]*w_k ----
  for (int i = t; i < 232*NHEADS; i += 256){
    int tap = i / NHEADS, h = i - tap*NHEADS;
    int s = tap >> 2;
    float v = scoreS[h*58 + s] * wtap[tap];
    atomicAdd(&agg[h*224 + (int)stap[tap]], v);
  }
  __syncthreads();

  // ---- P5: write agg16 (pads are zero) ----
  {
    _Float16* ar = agg16 + (size_t)blk*2688;
    for (int i = t; i < 2688; i += 256) ar[i] = (_Float16)agg[i];
  }
}

// -------- AV-GEMM: otok[tok][h*32+o] = sum_i agg[tok][h][i]*VprojT[b][h*32+o][i] + bv --
__global__ void __launch_bounds__(256) k_av(const _Float16* __restrict__ agg16,
                                            const _Float16* __restrict__ VprojT,
                                            const float* __restrict__ bv, float* __restrict__ otok){
  int t = threadIdx.x;
  int w = t>>6, lane = t&63, col = lane&15, quad = lane>>4;
  int m0 = blockIdx.x*64;
  int bh = blockIdx.y; int b = bh / 12, h = bh - b*12;
  const _Float16* ar = agg16 + ((size_t)(b*196 + min(m0 + w*16 + col, 195)))*2688 + h*224;
  f4 acc[2] = {{0,0,0,0},{0,0,0,0}};
  for (int kt = 0; kt < 7; ++kt){
    h8 a8 = *(const h8*)(ar + kt*32 + quad*8);
    #pragma unroll
    for (int nt = 0; nt < 2; ++nt){
      int o = h*32 + nt*16 + col;
      h8 b8 = *(const h8*)(VprojT + ((size_t)(b*384 + o))*224 + kt*32 + quad*8);
      acc[nt] = mfma16h(a8, b8, acc[nt]);
    }
  }
  #pragma unroll
  for (int nt = 0; nt < 2; ++nt){
    #pragma unroll
    for (int rr = 0; rr < 4; ++rr){
      int m = m0 + w*16 + quad*4 + rr;
      if (m < 196){
        int o = h*32 + nt*16 + col;
        otok[((size_t)(b*196 + m))*384 + o] = acc[nt][rr] + bv[o];
      }
    }
  }
}

extern "C" void kernel_launch(void* const* d_in, const int* in_sizes, int n_in,
                              void* d_out, int out_size, void* d_ws, size_t ws_size,
                              hipStream_t stream){
  const float* x    = (const float*)d_in[0];
  const float* Wq   = (const float*)d_in[1];
  const float* bq   = (const float*)d_in[2];
  const float* Wk   = (const float*)d_in[3];
  const float* bk   = (const float*)d_in[4];
  const float* Wv   = (const float*)d_in[5];
  const float* bv   = (const float*)d_in[6];
  const float* Wo1  = (const float*)d_in[7];
  const float* bo1  = (const float*)d_in[8];
  const float* Wdw  = (const float*)d_in[9];
  const float* bdw  = (const float*)d_in[10];
  const float* ln_g = (const float*)d_in[11];
  const float* ln_b = (const float*)d_in[12];
  const float* Wo2  = (const float*)d_in[13];
  const float* Wco  = (const float*)d_in[14];
  const float* pos  = (const float*)d_in[15];
  const float* Wp   = (const float*)d_in[16];
  const float* bp   = (const float*)d_in[17];
  float* out = (float*)d_out;

  float* ws   = (float*)d_ws;
  float* xh   = ws;                    // 602112 f32
  float* qf   = xh   + 602112;         // 602112
  float* t1   = qf   + 602112;         // 602112
  float* t2   = t1   + 602112;         // 150528
  float* offp = t2   + 150528;         // 153664
  float* otok = offp + 153664;         // 602112
  _Float16* xhh    = (_Float16*)(otok + 602112);   // 602112 h
  _Float16* K2h    = xhh    + 602112;              // 602112 h
  _Float16* VprojT = K2h    + 602112;              // 8*384*224 = 688128 h
  _Float16* G16    = VprojT + 688128;              // 1568*2352 = 3687936 h
  _Float16* agg16  = G16    + 3687936;             // 1568*2688 = 4214784 h

  k_transpose2<<<64, 256, 0, stream>>>(x, xh, xhh);
  k_mmf<3><<<dim3(25,6), 256, 0, stream>>>(xh, Wk,  nullptr, nullptr, K2h, NTOK, 384);
  k_mmf<0><<<dim3(25,6), 256, 0, stream>>>(xh, Wq,  bq,  qf, nullptr, NTOK, 384);
  k_mmf<1><<<dim3(25,6), 256, 0, stream>>>(qf, Wo1, bo1, t1, nullptr, NTOK, 384);
  k_dwln<<<392, 384, 0, stream>>>(t1, Wdw, bdw, ln_g, ln_b, t2);
  k_misc<<<241, 256, 0, stream>>>(t2, Wo2, offp, xhh, Wv, VprojT);
  k_qkt<<<dim3(4,96), 256, 0, stream>>>(qf, K2h, G16);
  k_fused<<<1568, 256, 0, stream>>>(qf, offp, G16, bk, Wco, pos, agg16);
  k_av<<<dim3(4,96), 256, 0, stream>>>(agg16, VprojT, bv, otok);
  k_mmf<2><<<dim3(25,6), 256, 0, stream>>>(otok, Wp, bp, out, nullptr, NTOK, 384);
}